// Round 3
// baseline (239.540 us; speedup 1.0000x reference)
//
#include <hip/hip_runtime.h>

// BlockSample R9: R6 structure + NON-TEMPORAL stores. Single-variable change.
//
// Evidence: R6 (LDS comb stores, 24 w/CU) ~67us, R7 (LDS linear, 12 w/CU)
// ~70us, R8 (no-LDS reg window, dep-free stores) ~72us -> store issue pattern,
// LDS, barriers, and TLP are all non-limiters. Writes cap at ~3.4 TB/s in all
// three while the harness 906MB fill hits 6.7 TB/s. Invariant difference: our
// 226.5MB output FITS in 256MB Infinity Cache -> dirty allocate/evict path;
// fill's 906MB forces pure streaming. Theory: cache-absorption caps writes.
// Fix: __builtin_nontemporal_store (global_store_dwordx4 nt) -> stream to HBM.
// Everything else is byte-identical to R6 (best-known 67us kernel).
// Prediction: kernel 67 -> ~45-52us, dur_us 226 -> 200-212.

#define BB 8
#define CC 192
#define HH 48
#define WW 48
#define G   16                 // channels per block
#define NCHG (CC / G)          // 12
#define YT  3                  // y's per block
#define NYG (HH / YT)          // 16
#define NROW (YT + 3)          // 6 staged rows per channel
#define PITCH 55               // 3 left pad + 48 + 4 spare; odd -> conflict-free
#define NBLK (BB * NCHG * NYG) // 1536 blocks = 6/CU exactly
#define NXCD 8

typedef float vfloat4 __attribute__((ext_vector_type(4)));

__global__ __launch_bounds__(256) void
blocksample_kernel(const float* __restrict__ in, float* __restrict__ out) {
    // XCD swizzle: contiguous (b,chg,yg) span per XCD; yg fastest so adjacent
    // tiles (sharing 3 halo rows) hit the same L2.
    const int id    = blockIdx.x;
    const int xcd   = id & (NXCD - 1);
    const int g     = xcd * (NBLK / NXCD) + (id >> 3);

    const int yg  = g % NYG;
    const int chg = (g / NYG) % NCHG;
    const int b   = g / (NYG * NCHG);
    const int y0  = yg * YT;

    __shared__ float lds[G * NROW * PITCH];       // 16 x 6 x 55 x 4B = 21,120 B

    const int t = threadIdx.x;

    // 1) zero the read halo: cols {1,2,51} of each of the 96 rows.
    for (int k = t; k < G * NROW * 3; k += 256) {
        const int rc = k / 3;
        const int m  = k - rc * 3;
        const int c  = (m == 0) ? 1 : ((m == 1) ? 2 : 51);
        lds[rc * PITCH + c] = 0.0f;
    }

    // 2) fill interior with float4 loads: rc = ch*NROW + dyr covers rows
    //    y0-3 .. y0+2 per channel; OOB rows written as zeros.
    const float* inb = in + ((size_t)(b * CC + chg * G) * HH) * WW;
    for (int f = t; f < G * NROW * (WW / 4); f += 256) {
        const int rc  = f / (WW / 4);             // 0..95
        const int c4  = f - rc * (WW / 4);        // 0..11
        const int ch  = rc / NROW;
        const int dyr = rc - ch * NROW;
        const int row = y0 - 3 + dyr;
        vfloat4 val = (vfloat4)(0.0f);
        if (row >= 0 && row < HH)
            val = *(const vfloat4*)(inb + ((size_t)(ch * HH + row)) * WW + c4 * 4);
        float* dst = lds + rc * PITCH + 3 + c4 * 4;
        dst[0] = val.x; dst[1] = val.y; dst[2] = val.z; dst[3] = val.w;
    }
    __syncthreads();

    // 3) stores: lane l -> (ch = l>>2, i = l&3); wave w covers x = w,w+4,...
    //    One 1KB-contiguous NT store per (y,x); per-pixel stride = CC*4 float4.
    const int w  = t >> 6;
    const int l  = t & 63;
    const int i  = l & 3;
    const int ch = l >> 2;
    const float* lbase = lds + (ch * NROW + i) * PITCH;

    vfloat4* outb = (vfloat4*)out
        + ((size_t)((b * HH + y0) * WW) * CC + chg * G) * 4 + l;

    for (int dy = 0; dy < YT; ++dy) {
        const float* lrow = lbase + dy * PITCH;
        vfloat4* orow = outb + (size_t)dy * (WW * CC * 4);
        for (int x = w; x < WW; x += 4) {
            const float* p = lrow + (x + 1);      // input col x-2 at LDS col x+1
            vfloat4 v;
            v.x = p[0];
            v.y = p[1];
            v.z = p[2];
            v.w = p[3];
            if (i == 3) { v.z = 0.0f; v.w = 0.0f; }  // masked taps (3,2),(3,3)
            __builtin_nontemporal_store(v, &orow[(size_t)x * (CC * 4)]);
        }
    }
}

extern "C" void kernel_launch(void* const* d_in, const int* in_sizes, int n_in,
                              void* d_out, int out_size, void* d_ws, size_t ws_size,
                              hipStream_t stream) {
    const float* in = (const float*)d_in[0];
    float* out = (float*)d_out;
    blocksample_kernel<<<dim3(NBLK), dim3(256), 0, stream>>>(in, out);
}